// Round 3
// baseline (63599.036 us; speedup 1.0000x reference)
//
#include <hip/hip_runtime.h>
#include <stdint.h>

// FPS: B=16, C=3, N=131072, M=2048 (derived from out_size).
// 256 blocks (16 per batch) x 1024 threads, 1 block/CU.
// R3 changes vs R2:
//  - Hand-unrolled named scalars (x0..x7 etc.): R2 showed VGPR_Count=32 +
//    WRITE_SIZE=19.4MB => per-thread arrays went to scratch. Force SROA.
//  - Flat per-WAVE barrier: each wave publishes its own u64 key (256
//    slots/batch), every wave spins on all 256 and reduces them itself.
//    Deletes both __syncthreads + LDS hops per iteration. Relaxed atomics:
//    all state rides in one u64 (tag|distbits|invidx); parity double-buffer
//    makes slot reuse race-free (publish t+2 requires all published t+1).
// Numerics (bit-matches XLA-CPU ref, verified R2): d = fma(dz,dz,fma(dy,dy,dx*dx)).

#define NBATCH    16
#define NPTS      131072
#define SUBBLOCKS 16
#define NTHREADS  1024
#define NWAVES    (NTHREADS / 64)        // 16
#define WSLOTS    (SUBBLOCKS * NWAVES)   // 256 wave-slots per batch
#define PPT       8

typedef unsigned long long u64;

__global__ __launch_bounds__(NTHREADS, 4)
void fps_kernel(const float* __restrict__ points,
                float* __restrict__ out,
                u64* __restrict__ slots, int M)
{
  const int bid   = blockIdx.x;
  // XCD swizzle heuristic (speed only): bid&7 ~ XCD; batch's 16 blocks colocate.
  const int xcd   = bid & 7;
  const int ord   = bid >> 3;
  const int batch = xcd * 2 + (ord >> 4);
  const int sub   = ord & 15;
  const int tid   = threadIdx.x;
  const int wave  = tid >> 6;
  const int lane  = tid & 63;

  const float* __restrict__ px = points + (size_t)batch * 3 * NPTS;
  const float* __restrict__ py = px + NPTS;
  const float* __restrict__ pz = px + 2 * NPTS;
  float* outb = out + (size_t)batch * 3 * M;
  u64* bslots = slots + (size_t)batch * 2 * WSLOTS;

  const int base = sub * (NPTS / SUBBLOCKS) + tid;   // thread's first point

  // 8 points/thread fully in NAMED registers (no arrays -> no scratch).
#define DECLP(i) float x##i, y##i, z##i, d##i;
  DECLP(0) DECLP(1) DECLP(2) DECLP(3) DECLP(4) DECLP(5) DECLP(6) DECLP(7)
#define LOADP(i) { int idx = base + (i << 10); \
    x##i = px[idx]; y##i = py[idx]; z##i = pz[idx]; d##i = __builtin_inff(); }
  LOADP(0) LOADP(1) LOADP(2) LOADP(3) LOADP(4) LOADP(5) LOADP(6) LOADP(7)

  // Selection 0 is index 0 by convention.
  if (sub == 0 && tid == 0) {
    outb[0]     = px[0];
    outb[M]     = py[0];
    outb[2 * M] = pz[0];
  }

  const int myslot = sub * NWAVES + wave;
  int sel = 0;

  for (int t = 1; t < M; ++t) {
    // Centroid = previously selected point (uniform broadcast load, L2-hot).
    float cx = px[sel], cy = py[sel], cz = pz[sel];

    float best = -1.0f;
    int bidx = 0;
    // d = fma(dz,dz, fma(dy,dy, dx*dx)) : bit-matches the reference.
    // strict '>' keeps the smallest index on ties (i ascending => idx ascending).
#define STEP(i) { \
    float dx = __fsub_rn(x##i, cx); \
    float dy = __fsub_rn(y##i, cy); \
    float dz = __fsub_rn(z##i, cz); \
    float dd = __builtin_fmaf(dz, dz, __builtin_fmaf(dy, dy, __fmul_rn(dx, dx))); \
    d##i = d##i < dd ? d##i : dd; \
    if (d##i > best) { best = d##i; bidx = base + (i << 10); } }
    STEP(0) STEP(1) STEP(2) STEP(3) STEP(4) STEP(5) STEP(6) STEP(7)

    // Pack: [tag @49][distBits:32 @17][invIdx:17 @0]. Non-negative f32 bits
    // are order-preserving; invIdx breaks ties toward the SMALLEST index.
    u64 key = ((u64)__float_as_uint(best) << 17) | (u64)((NPTS - 1) - bidx);

    // Wave (64-lane) butterfly max-reduce of the local key.
#pragma unroll
    for (int m = 32; m >= 1; m >>= 1) {
      u64 o = __shfl_xor(key, m, 64);
      key = o > key ? o : key;
    }

    // Publish this wave's key, tagged with t, in the parity buffer.
    u64* par = bslots + (size_t)(t & 1) * WSLOTS;
    if (lane == 0) {
      __hip_atomic_store(par + myslot, ((u64)t << 49) | key,
                         __ATOMIC_RELAXED, __HIP_MEMORY_SCOPE_AGENT);
    }

    // Every wave spins on all 256 slots: lane polls its 4 consecutive slots.
    const u64* pp = par + 4 * lane;
    u64 v0, v1, v2, v3;
    for (;;) {
      v0 = __hip_atomic_load(pp + 0, __ATOMIC_RELAXED, __HIP_MEMORY_SCOPE_AGENT);
      v1 = __hip_atomic_load(pp + 1, __ATOMIC_RELAXED, __HIP_MEMORY_SCOPE_AGENT);
      v2 = __hip_atomic_load(pp + 2, __ATOMIC_RELAXED, __HIP_MEMORY_SCOPE_AGENT);
      v3 = __hip_atomic_load(pp + 3, __ATOMIC_RELAXED, __HIP_MEMORY_SCOPE_AGENT);
      bool ok = ((unsigned)(v0 >> 49) == (unsigned)t) &
                ((unsigned)(v1 >> 49) == (unsigned)t) &
                ((unsigned)(v2 >> 49) == (unsigned)t) &
                ((unsigned)(v3 >> 49) == (unsigned)t);
      if (ok) break;
    }
    // All tags equal t => raw u64 compare == key compare.
    u64 k01 = v0 > v1 ? v0 : v1;
    u64 k23 = v2 > v3 ? v2 : v3;
    u64 k   = k01 > k23 ? k01 : k23;
#pragma unroll
    for (int m = 32; m >= 1; m >>= 1) {
      u64 o = __shfl_xor(k, m, 64);
      k = o > k ? o : k;
    }

    sel = (NPTS - 1) - (int)(k & 0x1FFFF);

    if (sub == 0 && tid == 0) {
      outb[t]         = px[sel];
      outb[M + t]     = py[sel];
      outb[2 * M + t] = pz[sel];
    }
  }
}

extern "C" void kernel_launch(void* const* d_in, const int* in_sizes, int n_in,
                              void* d_out, int out_size, void* d_ws, size_t ws_size,
                              hipStream_t stream) {
  (void)in_sizes; (void)n_in; (void)ws_size;
  const float* points = (const float*)d_in[0];
  float* out = (float*)d_out;
  u64* slots = (u64*)d_ws;
  const int M = out_size / (NBATCH * 3);   // 2048

  // Zero all barrier slots (tags must not collide with 1..M-1).
  hipMemsetAsync(d_ws, 0, (size_t)NBATCH * 2 * WSLOTS * sizeof(u64), stream);

  hipLaunchKernelGGL(fps_kernel, dim3(NBATCH * SUBBLOCKS), dim3(NTHREADS), 0,
                     stream, points, out, slots, M);
}

// Round 4
// 4486.330 us; speedup vs baseline: 14.1762x; 14.1762x over previous
//
#include <hip/hip_runtime.h>
#include <stdint.h>

// FPS: B=16, C=3, N=131072, M=2048 (derived from out_size).
// 256 blocks (16 per batch) x 1024 threads, 1 block/CU (96 KB LDS).
//
// R4 vs R2/R3 (evidence-driven):
//  - R2/R3 showed VGPR_Count=32: compiler sinks xyz loads into the loop ->
//    96 KB/CU re-read from L1/L2 every iteration. Fix: stage xyz in LDS
//    (3 planar f32[8192] = 96 KB), deterministic ~6cyc ds_read path.
//    Only dist (8 floats) must survive in registers.
//  - R3's flat per-wave barrier (256 pollers/batch, relaxed agent atomics)
//    exploded FETCH_SIZE to 690 MB (fabric polling congestion). Back to R2's
//    block-aggregated 16-slot/batch barrier, wave0-only spinner, but with a
//    CONVERGED poll loop (ballot all-match exit) so each round is ONE
//    coalesced 128 B line read, not 16 divergent transactions.
// Numerics (bit-matches ref, verified R2): d = fma(dz,dz, fma(dy,dy, dx*dx)).

#define NBATCH    16
#define NPTS      131072
#define SUBBLOCKS 16
#define NTHREADS  1024
#define CHUNK     (NPTS / SUBBLOCKS)   // 8192 points per block
#define PPT       (CHUNK / NTHREADS)   // 8

typedef unsigned long long u64;

__global__ __launch_bounds__(NTHREADS, 4)
void fps_kernel(const float* __restrict__ points,
                float* __restrict__ out,
                u64* __restrict__ slots, int M)
{
  __shared__ __align__(16) float xs[CHUNK];
  __shared__ __align__(16) float ys[CHUNK];
  __shared__ __align__(16) float zs[CHUNK];
  __shared__ u64 wkeys[NTHREADS / 64];
  __shared__ u64 winner_s;

  const int bid   = blockIdx.x;
  // XCD swizzle heuristic (speed only): batch's 16 blocks colocate on one XCD.
  const int xcd   = bid & 7;
  const int ord   = bid >> 3;
  const int batch = xcd * 2 + (ord >> 4);
  const int sub   = ord & 15;
  const int tid   = threadIdx.x;
  const int wave  = tid >> 6;
  const int lane  = tid & 63;

  const float* __restrict__ px = points + (size_t)batch * 3 * NPTS;
  const float* __restrict__ py = px + NPTS;
  const float* __restrict__ pz = px + 2 * NPTS;
  float* outb = out + (size_t)batch * 3 * M;
  u64* bslots = slots + (size_t)batch * 2 * SUBBLOCKS;

  // Stage this block's 8192-point chunk into LDS (coalesced float4 loads).
  const int cbase = sub * CHUNK;
#pragma unroll
  for (int k = 0; k < CHUNK / (NTHREADS * 4); ++k) {   // 2 iterations
    int o = k * NTHREADS * 4 + tid * 4;
    float4 vx = *(const float4*)(px + cbase + o);
    float4 vy = *(const float4*)(py + cbase + o);
    float4 vz = *(const float4*)(pz + cbase + o);
    *(float4*)(xs + o) = vx;
    *(float4*)(ys + o) = vy;
    *(float4*)(zs + o) = vz;
  }

  // Persistent per-thread state: just 8 dist floats (will stay in VGPRs).
  float d0, d1, d2, d3, d4, d5, d6, d7;
  d0 = d1 = d2 = d3 = d4 = d5 = d6 = d7 = __builtin_inff();

  // Selection 0 is index 0 by convention.
  if (sub == 0 && tid == 0) {
    outb[0]     = px[0];
    outb[M]     = py[0];
    outb[2 * M] = pz[0];
  }

  __syncthreads();   // LDS staging complete

  int sel = 0;
  for (int t = 1; t < M; ++t) {
    // Centroid = previously selected point (uniform broadcast load, L2-hot).
    float cx = px[sel], cy = py[sel], cz = pz[sel];

    float best = -1.0f;
    int bidx = 0;
    // d = fma(dz,dz, fma(dy,dy, dx*dx)) : bit-matches the reference chain.
    // strict '>' keeps the smallest index on ties (i ascending => idx ascending).
#define STEP(i) { \
    float dx = __fsub_rn(xs[tid + (i << 10)], cx); \
    float dy = __fsub_rn(ys[tid + (i << 10)], cy); \
    float dz = __fsub_rn(zs[tid + (i << 10)], cz); \
    float dd = __builtin_fmaf(dz, dz, __builtin_fmaf(dy, dy, __fmul_rn(dx, dx))); \
    d##i = d##i < dd ? d##i : dd; \
    if (d##i > best) { best = d##i; bidx = cbase + tid + (i << 10); } }
    STEP(0) STEP(1) STEP(2) STEP(3) STEP(4) STEP(5) STEP(6) STEP(7)

    // Pack: [tag @49][distBits:32 @17][invIdx:17 @0]. Non-negative f32 bits
    // are order-preserving; invIdx breaks ties toward the SMALLEST index.
    u64 key = ((u64)__float_as_uint(best) << 17) | (u64)((NPTS - 1) - bidx);

    // Wave (64-lane) butterfly max-reduce.
#pragma unroll
    for (int m = 32; m >= 1; m >>= 1) {
      u64 o = __shfl_xor(key, m, 64);
      key = o > key ? o : key;
    }
    if (lane == 0) wkeys[wave] = key;
    __syncthreads();

    if (wave == 0) {
      // Final block reduce: lanes mirror wkeys[lane&15] (LDS broadcast reads),
      // 4-step butterfly within each 16-lane group.
      u64 k = wkeys[lane & 15];
#pragma unroll
      for (int m = 8; m >= 1; m >>= 1) {
        u64 o = __shfl_xor(k, m, 64);
        k = o > k ? o : k;
      }
      u64* par = bslots + (size_t)(t & 1) * SUBBLOCKS;
      if (lane == 0) {
        __hip_atomic_store(par + sub, ((u64)t << 49) | k,
                           __ATOMIC_RELAXED, __HIP_MEMORY_SCOPE_AGENT);
      }
      // Converged poll: every lane reads slot (lane&15) -> one coalesced
      // 128 B line per round; exit only when ALL tags match t.
      const u64* pp = par + (lane & 15);
      u64 v;
      for (;;) {
        v = __hip_atomic_load(pp, __ATOMIC_RELAXED, __HIP_MEMORY_SCOPE_AGENT);
        if (__ballot((unsigned)(v >> 49) == (unsigned)t) == ~0ull) break;
      }
#pragma unroll
      for (int m = 8; m >= 1; m >>= 1) {
        u64 o = __shfl_xor(v, m, 64);
        v = o > v ? o : v;
      }
      if (lane == 0) winner_s = v;
    }
    __syncthreads();

    sel = (NPTS - 1) - (int)(winner_s & 0x1FFFF);

    if (sub == 0 && tid == 0) {
      outb[t]         = px[sel];
      outb[M + t]     = py[sel];
      outb[2 * M + t] = pz[sel];
    }
  }
}

extern "C" void kernel_launch(void* const* d_in, const int* in_sizes, int n_in,
                              void* d_out, int out_size, void* d_ws, size_t ws_size,
                              hipStream_t stream) {
  (void)in_sizes; (void)n_in; (void)ws_size;
  const float* points = (const float*)d_in[0];
  float* out = (float*)d_out;
  u64* slots = (u64*)d_ws;
  const int M = out_size / (NBATCH * 3);   // 2048

  // Zero barrier slots (stale tags from a previous launch could alias t).
  hipMemsetAsync(d_ws, 0, (size_t)NBATCH * 2 * SUBBLOCKS * sizeof(u64), stream);

  hipLaunchKernelGGL(fps_kernel, dim3(NBATCH * SUBBLOCKS), dim3(NTHREADS), 0,
                     stream, points, out, slots, M);
}